// Round 4
// baseline (8058.384 us; speedup 1.0000x reference)
//
#include <hip/hip_runtime.h>
#include <math.h>

#define BATCH 256
#define TT    127      // T-1 time steps
#define DD    512
#define HH    512
#define GG    2048     // 4*H
#define NWG   256
#define NTHR  256
#define OUT0_ELEMS ((size_t)BATCH * TT * DD)   // 16,646,144

typedef __attribute__((ext_vector_type(8))) short  short8;
typedef __attribute__((ext_vector_type(4))) float  floatx4;

__device__ __forceinline__ float bf2f(unsigned short u) {
    unsigned int x = ((unsigned int)u) << 16;
    return __builtin_bit_cast(float, x);
}
__device__ __forceinline__ unsigned short f2bf(float f) {
    unsigned int x = __builtin_bit_cast(unsigned int, f);
    unsigned int lsb = (x >> 16) & 1u;
    x += 0x7fffu + lsb;                 // round-to-nearest-even
    return (unsigned short)(x >> 16);
}

// Detect whether a buffer of ~N(0,1) values is stored as f32 or bf16.
// bf16: even-index ushorts have exponent field in [112,133] ~99.9% of the
// time; f32 little-endian: even ushorts are low mantissa bits (~9% pass).
__device__ __forceinline__ int detect_is_f32(const unsigned short* p) {
    int cnt = 0;
    for (int i = 0; i < 64; ++i) {
        int e = (p[2 * i] >> 7) & 0xFF;
        cnt += (e >= 112 && e <= 133) ? 1 : 0;
    }
    return cnt < 32;
}

// A-fragment load: 8 contiguous K elements, bf16 direct or f32->bf16.
__device__ __forceinline__ short8 load_a8(const void* base, size_t off, int f32m) {
    if (!f32m) return *(const short8*)((const unsigned short*)base + off);
    const float* fp = (const float*)base + off;
    short8 r;
#pragma unroll
    for (int j = 0; j < 8; ++j) r[j] = (short)f2bf(fp[j]);
    return r;
}

// ---------------------------------------------------------------------------
// Kernel 0: detect dtype; publish flag; bsum = b_ih + b_hh (f32);
// if f32 world, convert W_ih/W_hh to bf16 in ws.
// ---------------------------------------------------------------------------
__global__ __launch_bounds__(256) void prep_kernel(
    const void* __restrict__ W_ih, const void* __restrict__ W_hh,
    const void* __restrict__ b_ih, const void* __restrict__ b_hh,
    const unsigned short* __restrict__ x_u,
    unsigned short* __restrict__ wih_bf, unsigned short* __restrict__ whh_bf,
    float* __restrict__ bsum, int* __restrict__ flag_ws)
{
    __shared__ int sflag;
    if (threadIdx.x == 0) sflag = detect_is_f32(x_u);
    __syncthreads();
    const int f32m = sflag;
    const int gid = blockIdx.x * 256 + threadIdx.x;
    const int gsz = gridDim.x * 256;
    if (gid == 0) *flag_ws = f32m;

    for (int i = gid; i < 3 * GG; i += gsz) {
        float bi = f32m ? ((const float*)b_ih)[i] : bf2f(((const unsigned short*)b_ih)[i]);
        float bh = f32m ? ((const float*)b_hh)[i] : bf2f(((const unsigned short*)b_hh)[i]);
        bsum[i] = bi + bh;
    }
    if (f32m) {
        const float* wi = (const float*)W_ih;
        const float* wh = (const float*)W_hh;
        const int n = 3 * GG * DD;
        for (int i = gid; i < n; i += gsz) {
            wih_bf[i] = f2bf(wi[i]);
            whh_bf[i] = f2bf(wh[i]);
        }
    }
}

// ---------------------------------------------------------------------------
// Kernel 1: time-invariant input attention.
// h/c/bias logit terms are constant over d and cancel in softmax_d, so
// attn[b,:] = softmax_d( sum_t x[b,t,d]*attn_w[2H+t] ), constant over time.
// out0[b,t,d] = attn[b,d]*x[b,t,d]  (also consumed by LSTM layer 0).
// ---------------------------------------------------------------------------
__global__ __launch_bounds__(512) void attn_kernel(
    const void* __restrict__ xv,       // [B][TT][DD]
    const void* __restrict__ attn_wv,  // [2H+TT]
    void* __restrict__ outv,           // output 0 region
    const int* __restrict__ flag_ws)
{
    __shared__ float red[512];
    __shared__ float wx[TT];
    __shared__ int sflag;
    const int b = blockIdx.x;
    const int d = threadIdx.x;          // 0..511
    if (d == 0) sflag = *flag_ws;
    __syncthreads();
    const int f32m = sflag;

    if (d < TT)
        wx[d] = f32m ? ((const float*)attn_wv)[2 * HH + d]
                     : bf2f(((const unsigned short*)attn_wv)[2 * HH + d]);
    __syncthreads();

    const size_t xb = (size_t)b * TT * DD;
    float s = 0.f;
    for (int t = 0; t < TT; ++t) {
        size_t ix = xb + (size_t)t * DD + d;
        float xval = f32m ? ((const float*)xv)[ix] : bf2f(((const unsigned short*)xv)[ix]);
        s += xval * wx[t];
    }

    red[d] = s; __syncthreads();
    for (int off = 256; off > 0; off >>= 1) {
        if (d < off) red[d] = fmaxf(red[d], red[d + off]);
        __syncthreads();
    }
    const float m = red[0]; __syncthreads();
    const float e = expf(s - m);
    red[d] = e; __syncthreads();
    for (int off = 256; off > 0; off >>= 1) {
        if (d < off) red[d] += red[d + off];
        __syncthreads();
    }
    const float a = e / red[0];

    for (int t = 0; t < TT; ++t) {
        size_t ix = xb + (size_t)t * DD + d;
        float xval = f32m ? ((const float*)xv)[ix] : bf2f(((const unsigned short*)xv)[ix]);
        float v = a * xval;
        if (f32m) ((float*)outv)[ix] = v;
        else      ((unsigned short*)outv)[ix] = f2bf(v);
    }
}

// ---------------------------------------------------------------------------
// Kernel 2: persistent 3-layer LSTM, software wavefront over (tick, layer):
// at tick k layer l processes t = k-l; one grid barrier per tick.
// PLAIN launch: 256 blocks (4 waves, 33.8KB LDS each) -> capacity 4/CU,
// all blocks resident immediately on a 256-CU device.
// Barrier hardening vs cross-XCD L2 non-coherence:
//   - spin uses atomic fetch_add(0) (RMW -> forced to LLC coherence point;
//     an acquire *load* could be served stale from the per-XCD L2 forever)
//   - sticky watchdog: >4M spins -> give up all remaining barriers
//     (finite wrong answer instead of a hung container)
// 256 wgs = 8 batch-tiles(32) x 32 hidden-slices(16), XCD-swizzled.
// Gates[32x64] via mfma_f32_16x16x32_bf16, K split over 4 waves; partials
// combined in LDS; c-state in registers (fixed cell->thread map).
// ---------------------------------------------------------------------------
__global__ __launch_bounds__(256) void lstm_kernel(
    void* __restrict__ outv,                  // d_out: read out0 (l0 input), write out1
    const unsigned short* __restrict__ W_ih_o,
    const unsigned short* __restrict__ W_hh_o,
    const unsigned short* __restrict__ wih_bf,
    const unsigned short* __restrict__ whh_bf,
    const float* __restrict__ bsum,           // [3][GG]
    unsigned short* __restrict__ h_ws,        // [3][2][B][HH] bf16 parity dbuf
    unsigned* __restrict__ bar,               // [0]=count [1]=generation
    const int* __restrict__ flag_ws)
{
    __shared__ float g_lds[16 * 16 * 33];     // [q*4+g][hid16][batch32 +pad]
    __shared__ int sflag;
    __shared__ int s_dead;

    const int tid    = threadIdx.x;
    if (tid == 0) { sflag = *flag_ws; s_dead = 0; }
    __syncthreads();
    const int f32m = sflag;

    const unsigned short* WiB = f32m ? wih_bf : W_ih_o;
    const unsigned short* WhB = f32m ? whh_bf : W_hh_o;

    const int lane   = tid & 63;
    const int wv     = tid >> 6;              // wave id 0..3 = K-quarter
    const int m_lane = lane & 15;
    const int kq     = lane >> 4;

    const int blk = blockIdx.x;
    const int xcd = blk & 7;
    const int loc = blk >> 3;
    const int hi  = xcd * 4 + (loc & 3);      // hidden slice 0..31
    const int bi  = loc >> 2;                 // batch tile 0..7
    const int hid0 = hi * 16;
    const int b0   = bi * 32;

    float c_reg[3][2];
#pragma unroll
    for (int l = 0; l < 3; ++l) { c_reg[l][0] = 0.f; c_reg[l][1] = 0.f; }

    for (int k = 0; k < TT + 2; ++k) {
        for (int l = 0; l < 3; ++l) {
            const int t = k - l;
            if (t < 0 || t >= TT) continue;   // uniform across wgs & threads

            const unsigned short* hsrc = (l == 0) ? (const unsigned short*)0
                : (h_ws + ((size_t)(l - 1) * 2 + (t & 1)) * BATCH * HH);
            const unsigned short* hprev =
                h_ws + ((size_t)l * 2 + ((t - 1) & 1)) * BATCH * HH;
            const unsigned short* Wi = WiB + (size_t)l * GG * DD;
            const unsigned short* Wh = WhB + (size_t)l * GG * DD;

            floatx4 acc[2][4];
#pragma unroll
            for (int mt = 0; mt < 2; ++mt)
#pragma unroll
                for (int g = 0; g < 4; ++g) {
                    floatx4 z = {0.f, 0.f, 0.f, 0.f};
                    acc[mt][g] = z;
                }

#pragma unroll
            for (int kk = 0; kk < 4; ++kk) {
                const int k0 = (wv * 4 + kk) * 32 + kq * 8;
                short8 a0, a1;
                if (l == 0) {
                    a0 = load_a8(outv, ((size_t)(b0 + m_lane) * TT + t) * DD + k0, f32m);
                    a1 = load_a8(outv, ((size_t)(b0 + 16 + m_lane) * TT + t) * DD + k0, f32m);
                } else {
                    a0 = *(const short8*)(hsrc + (size_t)(b0 + m_lane) * HH + k0);
                    a1 = *(const short8*)(hsrc + (size_t)(b0 + 16 + m_lane) * HH + k0);
                }
#pragma unroll
                for (int g = 0; g < 4; ++g) {
                    short8 bfr = *(const short8*)(Wi + (size_t)(g * HH + hid0 + m_lane) * DD + k0);
                    acc[0][g] = __builtin_amdgcn_mfma_f32_16x16x32_bf16(a0, bfr, acc[0][g], 0, 0, 0);
                    acc[1][g] = __builtin_amdgcn_mfma_f32_16x16x32_bf16(a1, bfr, acc[1][g], 0, 0, 0);
                }
                short8 h0f = *(const short8*)(hprev + (size_t)(b0 + m_lane) * HH + k0);
                short8 h1f = *(const short8*)(hprev + (size_t)(b0 + 16 + m_lane) * HH + k0);
#pragma unroll
                for (int g = 0; g < 4; ++g) {
                    short8 bfr = *(const short8*)(Wh + (size_t)(g * HH + hid0 + m_lane) * DD + k0);
                    acc[0][g] = __builtin_amdgcn_mfma_f32_16x16x32_bf16(h0f, bfr, acc[0][g], 0, 0, 0);
                    acc[1][g] = __builtin_amdgcn_mfma_f32_16x16x32_bf16(h1f, bfr, acc[1][g], 0, 0, 0);
                }
            }

            // combine 4 waves' K-partials in LDS
            __syncthreads();
#pragma unroll
            for (int mt = 0; mt < 2; ++mt)
#pragma unroll
                for (int g = 0; g < 4; ++g)
#pragma unroll
                    for (int r = 0; r < 4; ++r)
                        g_lds[((wv * 4 + g) * 16 + m_lane) * 33 + mt * 16 + kq * 4 + r]
                            = acc[mt][g][r];
            __syncthreads();

            // epilogue: 512 cells over 256 threads; fixed cell->thread map
#pragma unroll
            for (int it = 0; it < 2; ++it) {
                const int idx = tid + it * 256;
                const int hid = idx & 15;
                const int bl  = idx >> 4;     // 0..31
                float gv[4];
#pragma unroll
                for (int g = 0; g < 4; ++g) {
                    float sum = 0.f;
#pragma unroll
                    for (int q = 0; q < 4; ++q)
                        sum += g_lds[((q * 4 + g) * 16 + hid) * 33 + bl];
                    sum += bsum[l * GG + g * HH + hid0 + hid];
                    gv[g] = sum;
                }
                const float ig = 1.f / (1.f + expf(-gv[0]));
                const float fg = 1.f / (1.f + expf(-gv[1]));
                const float gg = tanhf(gv[2]);
                const float og = 1.f / (1.f + expf(-gv[3]));

                const float cnew = fg * c_reg[l][it] + ig * gg;
                c_reg[l][it] = cnew;
                const float hnew = og * tanhf(cnew);

                const int bgl  = b0 + bl;
                const int hidg = hid0 + hid;
                h_ws[(((size_t)l * 2 + (t & 1)) * BATCH + bgl) * HH + hidg] = f2bf(hnew);
                if (l == 2) {
                    const size_t ox = OUT0_ELEMS + ((size_t)bgl * TT + t) * HH + hidg;
                    if (f32m) ((float*)outv)[ox] = hnew;
                    else      ((unsigned short*)outv)[ox] = f2bf(hnew);
                }
            }
        }

        if (k < TT + 1) {
            __syncthreads();
            if (tid == 0) {
                __threadfence();              // release: writeback this XCD's L2
                if (!s_dead) {
                    unsigned arrived = __hip_atomic_fetch_add(&bar[0], 1u,
                                            __ATOMIC_ACQ_REL, __HIP_MEMORY_SCOPE_AGENT);
                    if (arrived == NWG - 1) {
                        __hip_atomic_store(&bar[0], 0u,
                                           __ATOMIC_RELAXED, __HIP_MEMORY_SCOPE_AGENT);
                        __hip_atomic_fetch_add(&bar[1], 1u,
                                           __ATOMIC_RELEASE, __HIP_MEMORY_SCOPE_AGENT);
                    } else {
                        int spins = 0;
                        // RMW spin: forced to LLC, cannot be served stale
                        while (__hip_atomic_fetch_add(&bar[1], 0u, __ATOMIC_ACQUIRE,
                                                      __HIP_MEMORY_SCOPE_AGENT)
                               <= (unsigned)k) {
                            __builtin_amdgcn_s_sleep(4);
                            if (++spins > 4000000) { s_dead = 1; break; }
                        }
                    }
                }
                __threadfence();              // acquire: invalidate before reads
            }
            __syncthreads();
        }
    }
}

// ---------------------------------------------------------------------------
// workspace layout (bytes)
// ---------------------------------------------------------------------------
#define WIH_OFF  ((size_t)0)
#define WIH_SZ   ((size_t)3 * GG * DD * 2)          // 6,291,456
#define WHH_OFF  (WIH_OFF + WIH_SZ)
#define WHH_SZ   WIH_SZ
#define BSUM_OFF (WHH_OFF + WHH_SZ)
#define BSUM_SZ  ((size_t)3 * GG * 4)               // 24,576
#define H_OFF    (BSUM_OFF + BSUM_SZ)
#define H_SZ     ((size_t)3 * 2 * BATCH * HH * 2)   // 1,572,864
#define BAR_OFF  (H_OFF + H_SZ)
#define FLAG_OFF (BAR_OFF + 32)
#define WS_NEED  (BAR_OFF + 64)                     // ~14.2 MB

extern "C" void kernel_launch(void* const* d_in, const int* in_sizes, int n_in,
                              void* d_out, int out_size, void* d_ws, size_t ws_size,
                              hipStream_t stream) {
    (void)in_sizes; (void)n_in; (void)out_size;

    const void* x      = d_in[0];
    const void* W_ih   = d_in[1];
    const void* W_hh   = d_in[2];
    const void* b_ih   = d_in[3];
    const void* b_hh   = d_in[4];
    const void* attn_w = d_in[5];
    // d_in[6] (attn_b) cancels in the softmax — unused.

    char* ws = (char*)d_ws;
    unsigned short* wih_bf = (unsigned short*)(ws + WIH_OFF);
    unsigned short* whh_bf = (unsigned short*)(ws + WHH_OFF);
    float*          bsum   = (float*)(ws + BSUM_OFF);
    unsigned short* h_ws   = (unsigned short*)(ws + H_OFF);
    unsigned*       bar    = (unsigned*)(ws + BAR_OFF);
    int*            flagp  = (int*)(ws + FLAG_OFF);

    if (ws_size < WS_NEED) return;

    // zero h (both parities) + barrier/flag block every call
    hipMemsetAsync(ws + H_OFF, 0, H_SZ + 64, stream);

    prep_kernel<<<dim3(1024), dim3(256), 0, stream>>>(
        W_ih, W_hh, b_ih, b_hh, (const unsigned short*)x,
        wih_bf, whh_bf, bsum, flagp);

    attn_kernel<<<dim3(BATCH), dim3(512), 0, stream>>>(x, attn_w, d_out, flagp);

    lstm_kernel<<<dim3(NWG), dim3(NTHR), 0, stream>>>(
        d_out, (const unsigned short*)W_ih, (const unsigned short*)W_hh,
        wih_bf, whh_bf, bsum, h_ws, bar, flagp);
}

// Round 5
// 5567.144 us; speedup vs baseline: 1.4475x; 1.4475x over previous
//
#include <hip/hip_runtime.h>
#include <math.h>

#define BATCH 256
#define TT    127      // T-1 time steps
#define DD    512
#define HH    512
#define GG    2048     // 4*H
#define NWG   256
#define NTHR  256
#define OUT0_ELEMS ((size_t)BATCH * TT * DD)   // 16,646,144

typedef __attribute__((ext_vector_type(8))) short  short8;
typedef __attribute__((ext_vector_type(4))) float  floatx4;

__device__ __forceinline__ float bf2f(unsigned short u) {
    unsigned int x = ((unsigned int)u) << 16;
    return __builtin_bit_cast(float, x);
}
__device__ __forceinline__ unsigned short f2bf(float f) {
    unsigned int x = __builtin_bit_cast(unsigned int, f);
    unsigned int lsb = (x >> 16) & 1u;
    x += 0x7fffu + lsb;                 // round-to-nearest-even
    return (unsigned short)(x >> 16);
}

// Detect whether a buffer of ~N(0,1) values is stored as f32 or bf16.
__device__ __forceinline__ int detect_is_f32(const unsigned short* p) {
    int cnt = 0;
    for (int i = 0; i < 64; ++i) {
        int e = (p[2 * i] >> 7) & 0xFF;
        cnt += (e >= 112 && e <= 133) ? 1 : 0;
    }
    return cnt < 32;
}

// A-fragment load: 8 contiguous K elements, bf16 direct or f32->bf16.
__device__ __forceinline__ short8 load_a8(const void* base, size_t off, int f32m) {
    if (!f32m) return *(const short8*)((const unsigned short*)base + off);
    const float* fp = (const float*)base + off;
    short8 r;
#pragma unroll
    for (int j = 0; j < 8; ++j) r[j] = (short)f2bf(fp[j]);
    return r;
}

// Coherent (LLC-level, L2-bypassing) load of 8 bf16 = 16 B, as 2 u64 atomics.
// Agent-scope relaxed atomics need NO cache invalidate for cross-XCD reads.
__device__ __forceinline__ short8 load_h8(const unsigned short* p) {
    union { unsigned long long u[2]; short8 v; } t;
    t.u[0] = __hip_atomic_load((const unsigned long long*)p,
                               __ATOMIC_RELAXED, __HIP_MEMORY_SCOPE_AGENT);
    t.u[1] = __hip_atomic_load((const unsigned long long*)p + 1,
                               __ATOMIC_RELAXED, __HIP_MEMORY_SCOPE_AGENT);
    return t.v;
}

// ---------------------------------------------------------------------------
// Kernel 0: detect dtype; publish flag; bsum = b_ih + b_hh (f32);
// if f32 world, convert W_ih/W_hh to bf16 in ws.
// ---------------------------------------------------------------------------
__global__ __launch_bounds__(256) void prep_kernel(
    const void* __restrict__ W_ih, const void* __restrict__ W_hh,
    const void* __restrict__ b_ih, const void* __restrict__ b_hh,
    const unsigned short* __restrict__ x_u,
    unsigned short* __restrict__ wih_bf, unsigned short* __restrict__ whh_bf,
    float* __restrict__ bsum, int* __restrict__ flag_ws)
{
    __shared__ int sflag;
    if (threadIdx.x == 0) sflag = detect_is_f32(x_u);
    __syncthreads();
    const int f32m = sflag;
    const int gid = blockIdx.x * 256 + threadIdx.x;
    const int gsz = gridDim.x * 256;
    if (gid == 0) *flag_ws = f32m;

    for (int i = gid; i < 3 * GG; i += gsz) {
        float bi = f32m ? ((const float*)b_ih)[i] : bf2f(((const unsigned short*)b_ih)[i]);
        float bh = f32m ? ((const float*)b_hh)[i] : bf2f(((const unsigned short*)b_hh)[i]);
        bsum[i] = bi + bh;
    }
    if (f32m) {
        const float* wi = (const float*)W_ih;
        const float* wh = (const float*)W_hh;
        const int n = 3 * GG * DD;
        for (int i = gid; i < n; i += gsz) {
            wih_bf[i] = f2bf(wi[i]);
            whh_bf[i] = f2bf(wh[i]);
        }
    }
}

// ---------------------------------------------------------------------------
// Kernel 1: time-invariant input attention (h/c/bias terms cancel in
// softmax over d). out0[b,t,d] = softmax_d(sum_t x*w)[b,d] * x[b,t,d].
// ---------------------------------------------------------------------------
__global__ __launch_bounds__(512) void attn_kernel(
    const void* __restrict__ xv,       // [B][TT][DD]
    const void* __restrict__ attn_wv,  // [2H+TT]
    void* __restrict__ outv,           // output 0 region
    const int* __restrict__ flag_ws)
{
    __shared__ float red[512];
    __shared__ float wx[TT];
    __shared__ int sflag;
    const int b = blockIdx.x;
    const int d = threadIdx.x;          // 0..511
    if (d == 0) sflag = *flag_ws;
    __syncthreads();
    const int f32m = sflag;

    if (d < TT)
        wx[d] = f32m ? ((const float*)attn_wv)[2 * HH + d]
                     : bf2f(((const unsigned short*)attn_wv)[2 * HH + d]);
    __syncthreads();

    const size_t xb = (size_t)b * TT * DD;
    float s = 0.f;
    for (int t = 0; t < TT; ++t) {
        size_t ix = xb + (size_t)t * DD + d;
        float xval = f32m ? ((const float*)xv)[ix] : bf2f(((const unsigned short*)xv)[ix]);
        s += xval * wx[t];
    }

    red[d] = s; __syncthreads();
    for (int off = 256; off > 0; off >>= 1) {
        if (d < off) red[d] = fmaxf(red[d], red[d + off]);
        __syncthreads();
    }
    const float m = red[0]; __syncthreads();
    const float e = expf(s - m);
    red[d] = e; __syncthreads();
    for (int off = 256; off > 0; off >>= 1) {
        if (d < off) red[d] += red[d + off];
        __syncthreads();
    }
    const float a = e / red[0];

    for (int t = 0; t < TT; ++t) {
        size_t ix = xb + (size_t)t * DD + d;
        float xval = f32m ? ((const float*)xv)[ix] : bf2f(((const unsigned short*)xv)[ix]);
        float v = a * xval;
        if (f32m) ((float*)outv)[ix] = v;
        else      ((unsigned short*)outv)[ix] = f2bf(v);
    }
}

// ---------------------------------------------------------------------------
// Kernel 2: persistent 3-layer LSTM wavefront, one grid barrier per tick.
// INVALIDATE-FREE coherence design:
//   - mutable cross-block data (h_ws) is accessed ONLY via agent-scope
//     relaxed atomics (L2-bypassing, LLC-coherent) -> no buffer_inv needed
//   - barrier: arrival fetch_add RELEASE (drains h stores), spin fetch_add
//     RELAXED (never invalidates), counters on separate cachelines
//   - weights / x / bsum are read-only plain loads -> stay L2-resident
//     across all 129 ticks (R4 invalidated them every tick: 61us/tick)
// ---------------------------------------------------------------------------
__global__ __launch_bounds__(256) void lstm_kernel(
    void* __restrict__ outv,                  // d_out: read out0, write out1
    const unsigned short* __restrict__ W_ih_o,
    const unsigned short* __restrict__ W_hh_o,
    const unsigned short* __restrict__ wih_bf,
    const unsigned short* __restrict__ whh_bf,
    const float* __restrict__ bsum,           // [3][GG]
    unsigned short* __restrict__ h_ws,        // [3][2][B][HH] bf16 parity dbuf
    unsigned* __restrict__ bar,               // +0: arrivals, +32 (128B): gen
    const int* __restrict__ flag_ws)
{
    __shared__ float g_lds[16 * 16 * 33];     // [(q*4+g)*16+hid]*33 + batch
    __shared__ int sflag;
    __shared__ int s_dead;

    const int tid = threadIdx.x;
    if (tid == 0) { sflag = *flag_ws; s_dead = 0; }
    __syncthreads();
    const int f32m = sflag;

    const unsigned short* WiB = f32m ? wih_bf : W_ih_o;
    const unsigned short* WhB = f32m ? whh_bf : W_hh_o;

    const int lane   = tid & 63;
    const int wv     = tid >> 6;              // wave id 0..3 = K-quarter
    const int m_lane = lane & 15;
    const int kq     = lane >> 4;

    const int blk = blockIdx.x;
    const int xcd = blk & 7;
    const int loc = blk >> 3;
    const int hi  = xcd * 4 + (loc & 3);      // hidden slice 0..31
    const int bi  = loc >> 2;                 // batch tile 0..7
    const int hid0 = hi * 16;
    const int b0   = bi * 32;

    // epilogue ownership: thread -> (batch bl, hid pair hp)
    const int ep_bl = tid >> 3;               // 0..31
    const int ep_hp = tid & 7;                // hid pair, hids {2hp, 2hp+1}

    float c_reg[3][2];
#pragma unroll
    for (int l = 0; l < 3; ++l) { c_reg[l][0] = 0.f; c_reg[l][1] = 0.f; }

    unsigned* arrv = bar;
    unsigned* gen  = bar + 32;                // separate 128B cacheline

    for (int k = 0; k < TT + 2; ++k) {
        for (int l = 0; l < 3; ++l) {
            const int t = k - l;
            if (t < 0 || t >= TT) continue;   // uniform across wgs & threads

            const unsigned short* hsrc = (l == 0) ? (const unsigned short*)0
                : (h_ws + ((size_t)(l - 1) * 2 + (t & 1)) * BATCH * HH);
            const unsigned short* hprev =
                h_ws + ((size_t)l * 2 + ((t - 1) & 1)) * BATCH * HH;
            const unsigned short* Wi = WiB + (size_t)l * GG * DD;
            const unsigned short* Wh = WhB + (size_t)l * GG * DD;

            floatx4 acc[2][4];
#pragma unroll
            for (int mt = 0; mt < 2; ++mt)
#pragma unroll
                for (int g = 0; g < 4; ++g) {
                    floatx4 z = {0.f, 0.f, 0.f, 0.f};
                    acc[mt][g] = z;
                }

#pragma unroll
            for (int kk = 0; kk < 4; ++kk) {
                const int k0 = (wv * 4 + kk) * 32 + kq * 8;
                short8 a0, a1;
                if (l == 0) {
                    a0 = load_a8(outv, ((size_t)(b0 + m_lane) * TT + t) * DD + k0, f32m);
                    a1 = load_a8(outv, ((size_t)(b0 + 16 + m_lane) * TT + t) * DD + k0, f32m);
                } else {
                    a0 = load_h8(hsrc + (size_t)(b0 + m_lane) * HH + k0);
                    a1 = load_h8(hsrc + (size_t)(b0 + 16 + m_lane) * HH + k0);
                }
#pragma unroll
                for (int g = 0; g < 4; ++g) {
                    short8 bfr = *(const short8*)(Wi + (size_t)(g * HH + hid0 + m_lane) * DD + k0);
                    acc[0][g] = __builtin_amdgcn_mfma_f32_16x16x32_bf16(a0, bfr, acc[0][g], 0, 0, 0);
                    acc[1][g] = __builtin_amdgcn_mfma_f32_16x16x32_bf16(a1, bfr, acc[1][g], 0, 0, 0);
                }
                short8 h0f = load_h8(hprev + (size_t)(b0 + m_lane) * HH + k0);
                short8 h1f = load_h8(hprev + (size_t)(b0 + 16 + m_lane) * HH + k0);
#pragma unroll
                for (int g = 0; g < 4; ++g) {
                    short8 bfr = *(const short8*)(Wh + (size_t)(g * HH + hid0 + m_lane) * DD + k0);
                    acc[0][g] = __builtin_amdgcn_mfma_f32_16x16x32_bf16(h0f, bfr, acc[0][g], 0, 0, 0);
                    acc[1][g] = __builtin_amdgcn_mfma_f32_16x16x32_bf16(h1f, bfr, acc[1][g], 0, 0, 0);
                }
            }

            // combine 4 waves' K-partials in LDS
            __syncthreads();
#pragma unroll
            for (int mt = 0; mt < 2; ++mt)
#pragma unroll
                for (int g = 0; g < 4; ++g)
#pragma unroll
                    for (int r = 0; r < 4; ++r)
                        g_lds[((wv * 4 + g) * 16 + m_lane) * 33 + mt * 16 + kq * 4 + r]
                            = acc[mt][g][r];
            __syncthreads();

            // epilogue: each thread owns (bl, hid-pair) -> packed u32 h-store
            {
                float hout[2];
#pragma unroll
                for (int dlt = 0; dlt < 2; ++dlt) {
                    const int hid = 2 * ep_hp + dlt;
                    float gv[4];
#pragma unroll
                    for (int g = 0; g < 4; ++g) {
                        float sum = 0.f;
#pragma unroll
                        for (int q = 0; q < 4; ++q)
                            sum += g_lds[((q * 4 + g) * 16 + hid) * 33 + ep_bl];
                        sum += bsum[l * GG + g * HH + hid0 + hid];
                        gv[g] = sum;
                    }
                    const float ig = 1.f / (1.f + expf(-gv[0]));
                    const float fg = 1.f / (1.f + expf(-gv[1]));
                    const float gg = tanhf(gv[2]);
                    const float og = 1.f / (1.f + expf(-gv[3]));
                    const float cnew = fg * c_reg[l][dlt] + ig * gg;
                    c_reg[l][dlt] = cnew;
                    hout[dlt] = og * tanhf(cnew);
                }
                const int bgl  = b0 + ep_bl;
                const int hidg = hid0 + 2 * ep_hp;
                const unsigned hpk = (unsigned)f2bf(hout[0])
                                   | ((unsigned)f2bf(hout[1]) << 16);
                __hip_atomic_store(
                    (unsigned*)(h_ws + (((size_t)l * 2 + (t & 1)) * BATCH + bgl) * HH + hidg),
                    hpk, __ATOMIC_RELAXED, __HIP_MEMORY_SCOPE_AGENT);
                if (l == 2) {
                    const size_t ox = OUT0_ELEMS + ((size_t)bgl * TT + t) * HH + hidg;
                    if (f32m) {
                        ((float*)outv)[ox]     = hout[0];
                        ((float*)outv)[ox + 1] = hout[1];
                    } else {
                        *(unsigned*)((unsigned short*)outv + ox) = hpk;
                    }
                }
            }
        }

        if (k < TT + 1) {
            __syncthreads();
            if (tid == 0) {
                if (!s_dead) {
                    // RELEASE: waits vmcnt(0) (drains sc1 h stores to LLC) +
                    // writes back dirty L2; does NOT invalidate.
                    unsigned arrived = __hip_atomic_fetch_add(arrv, 1u,
                                            __ATOMIC_RELEASE, __HIP_MEMORY_SCOPE_AGENT);
                    if (arrived == NWG - 1) {
                        __hip_atomic_store(arrv, 0u,
                                           __ATOMIC_RELAXED, __HIP_MEMORY_SCOPE_AGENT);
                        __hip_atomic_fetch_add(gen, 1u,
                                           __ATOMIC_RELAXED, __HIP_MEMORY_SCOPE_AGENT);
                    } else {
                        int spins = 0;
                        // RELAXED RMW spin: LLC-coherent, never invalidates L2
                        while (__hip_atomic_fetch_add(gen, 0u, __ATOMIC_RELAXED,
                                                      __HIP_MEMORY_SCOPE_AGENT)
                               <= (unsigned)k) {
                            __builtin_amdgcn_s_sleep(8);
                            if (++spins > 2000000) { s_dead = 1; break; }
                        }
                    }
                }
            }
            __syncthreads();
        }
    }
}

// ---------------------------------------------------------------------------
// workspace layout (bytes)
// ---------------------------------------------------------------------------
#define WIH_OFF  ((size_t)0)
#define WIH_SZ   ((size_t)3 * GG * DD * 2)          // 6,291,456
#define WHH_OFF  (WIH_OFF + WIH_SZ)
#define WHH_SZ   WIH_SZ
#define BSUM_OFF (WHH_OFF + WHH_SZ)
#define BSUM_SZ  ((size_t)3 * GG * 4)               // 24,576
#define H_OFF    (BSUM_OFF + BSUM_SZ)
#define H_SZ     ((size_t)3 * 2 * BATCH * HH * 2)   // 1,572,864
#define BAR_OFF  (H_OFF + H_SZ)                     // arrivals @+0, gen @+128
#define FLAG_OFF (BAR_OFF + 192)
#define WS_NEED  (BAR_OFF + 256)                    // ~14.2 MB

extern "C" void kernel_launch(void* const* d_in, const int* in_sizes, int n_in,
                              void* d_out, int out_size, void* d_ws, size_t ws_size,
                              hipStream_t stream) {
    (void)in_sizes; (void)n_in; (void)out_size;

    const void* x      = d_in[0];
    const void* W_ih   = d_in[1];
    const void* W_hh   = d_in[2];
    const void* b_ih   = d_in[3];
    const void* b_hh   = d_in[4];
    const void* attn_w = d_in[5];
    // d_in[6] (attn_b) cancels in the softmax — unused.

    char* ws = (char*)d_ws;
    unsigned short* wih_bf = (unsigned short*)(ws + WIH_OFF);
    unsigned short* whh_bf = (unsigned short*)(ws + WHH_OFF);
    float*          bsum   = (float*)(ws + BSUM_OFF);
    unsigned short* h_ws   = (unsigned short*)(ws + H_OFF);
    unsigned*       bar    = (unsigned*)(ws + BAR_OFF);
    int*            flagp  = (int*)(ws + FLAG_OFF);

    if (ws_size < WS_NEED) return;

    // zero h (both parities) + barrier/flag block every call
    hipMemsetAsync(ws + H_OFF, 0, H_SZ + 256, stream);

    prep_kernel<<<dim3(1024), dim3(256), 0, stream>>>(
        W_ih, W_hh, b_ih, b_hh, (const unsigned short*)x,
        wih_bf, whh_bf, bsum, flagp);

    attn_kernel<<<dim3(BATCH), dim3(512), 0, stream>>>(x, attn_w, d_out, flagp);

    lstm_kernel<<<dim3(NWG), dim3(NTHR), 0, stream>>>(
        d_out, (const unsigned short*)W_ih, (const unsigned short*)W_hh,
        wih_bf, whh_bf, bsum, h_ws, bar, flagp);
}